// Round 2
// baseline (1974.132 us; speedup 1.0000x reference)
//
#include <hip/hip_runtime.h>

#define INV_SQRT2f 0.70710678118654752440f

// Analysis filters (compile-time; synthesis tap f[k] = AF[9-k], folded at call sites).
// Polyphase synthesis: out[2q+p] = sum_{j=0..4} AF[9-(2j+p)] * x[(q+2-j) mod Nin]
constexpr float FARv[2][2][10] = {
  {{0.0f, -0.08838834764832f, 0.08838834764832f, 0.69587998903400f, 0.69587998903400f,
    0.08838834764832f, -0.08838834764832f, 0.01122679215254f, 0.01122679215254f, 0.0f},
   {0.0f, -0.01122679215254f, 0.01122679215254f, 0.08838834764832f, 0.08838834764832f,
    -0.69587998903400f, 0.69587998903400f, -0.08838834764832f, -0.08838834764832f, 0.0f}},
  {{0.01122679215254f, 0.01122679215254f, -0.08838834764832f, 0.08838834764832f, 0.69587998903400f,
    0.69587998903400f, 0.08838834764832f, -0.08838834764832f, 0.0f, 0.0f},
   {0.0f, 0.0f, -0.08838834764832f, -0.08838834764832f, 0.69587998903400f,
    -0.69587998903400f, 0.08838834764832f, 0.08838834764832f, 0.01122679215254f, -0.01122679215254f}}
};
constexpr float DUALv[2][2][10] = {
  {{0.03516384f, 0.0f, -0.08832942f, 0.23389032f, 0.76027237f,
    0.58751830f, 0.0f, -0.11430184f, 0.0f, 0.0f},
   {0.0f, 0.0f, -0.11430184f, 0.0f, 0.58751830f,
    -0.76027237f, 0.23389032f, 0.08832942f, 0.0f, -0.03516384f}},
  {{0.0f, 0.0f, -0.11430184f, 0.0f, 0.58751830f,
    0.76027237f, 0.23389032f, -0.08832942f, 0.0f, 0.03516384f},
   {-0.03516384f, 0.0f, 0.08832942f, 0.23389032f, -0.76027237f,
    0.58751830f, 0.0f, -0.11430184f, 0.0f, 0.0f}}
};

__host__ __device__ constexpr float tap(bool farq, int t, int lh, int k) {
  return farq ? FARv[t][lh][k] : DUALv[t][lh][k];
}

// ---- staging: 12x12 spatial halo tile x 16 ch = 576 float4, 256 threads ----
template<int NSZ>
__device__ __forceinline__ void stage_copy(const float* __restrict__ src, float* __restrict__ dst,
                                           int ih0, int iw0, int tid) {
  #pragma unroll
  for (int it = 0; it < 3; ++it) {
    int e = tid + (it << 8);
    if (it < 2 || e < 576) {
      int r = e / 48;
      int cc = e - r * 48;
      int gr = (ih0 + r - 2) & (NSZ - 1);
      int gc = (iw0 + (cc >> 2) - 2) & (NSZ - 1);
      float4 v = *reinterpret_cast<const float4*>(src + (((size_t)gr * NSZ + gc) << 4) + ((cc & 3) << 2));
      *reinterpret_cast<float4*>(dst + (e << 2)) = v;
    }
  }
}

template<int NSZ>
__device__ __forceinline__ void stage_mix(const float* __restrict__ A, const float* __restrict__ B,
                                          float sgn, float* __restrict__ dst,
                                          int ih0, int iw0, int tid) {
  #pragma unroll
  for (int it = 0; it < 3; ++it) {
    int e = tid + (it << 8);
    if (it < 2 || e < 576) {
      int r = e / 48;
      int cc = e - r * 48;
      int gr = (ih0 + r - 2) & (NSZ - 1);
      int gc = (iw0 + (cc >> 2) - 2) & (NSZ - 1);
      size_t off = (((size_t)gr * NSZ + gc) << 4) + ((cc & 3) << 2);
      float4 a = *reinterpret_cast<const float4*>(A + off);
      float4 b = *reinterpret_cast<const float4*>(B + off);
      float4 v;
      v.x = (a.x + sgn * b.x) * INV_SQRT2f;
      v.y = (a.y + sgn * b.y) * INV_SQRT2f;
      v.z = (a.z + sgn * b.z) * INV_SQRT2f;
      v.w = (a.w + sgn * b.w) * INV_SQRT2f;
      *reinterpret_cast<float4*>(dst + (e << 2)) = v;
    }
  }
}

// ---- per-quadrant synthesis: col pass (LDS->reg), row pass (register-only) ----
// sIn layout: [plane(4)][r(12)][x(12)][c(16)]; thread owns (out-col nw=s, channel c).
template<bool FARQ, int M, int N>
__device__ __forceinline__ void synth_quad(const float* __restrict__ sIn, int s, int c,
                                           float (&acc)[16]) {
  const int pw = s & 1, qw = s >> 1;
  float flp[5], fhp[5];
  #pragma unroll
  for (int j = 0; j < 5; ++j) {
    flp[j] = pw ? tap(FARQ, N, 0, 8 - 2 * j) : tap(FARQ, N, 0, 9 - 2 * j);
    fhp[j] = pw ? tap(FARQ, N, 1, 8 - 2 * j) : tap(FARQ, N, 1, 9 - 2 * j);
  }
  float lo2[12], h2[12];
  #pragma unroll
  for (int r = 0; r < 12; ++r) {
    const float* r0 = sIn + ((0 * 12 + r) * 12) * 16 + c;
    const float* r1 = sIn + ((1 * 12 + r) * 12) * 16 + c;
    const float* r2 = sIn + ((2 * 12 + r) * 12) * 16 + c;
    const float* r3 = sIn + ((3 * 12 + r) * 12) * 16 + c;
    float lv = 0.f, hv = 0.f;
    #pragma unroll
    for (int j = 0; j < 5; ++j) {
      int x = (qw + 4 - j) << 4;
      lv += flp[j] * r0[x] + fhp[j] * r1[x];
      hv += flp[j] * r2[x] + fhp[j] * r3[x];
    }
    lo2[r] = lv; h2[r] = hv;
  }
  #pragma unroll
  for (int nh = 0; nh < 16; ++nh) {
    const int ph = nh & 1, qh = nh >> 1;
    float v = 0.f;
    #pragma unroll
    for (int j = 0; j < 5; ++j) {
      v += tap(FARQ, M, 0, 9 - (2 * j + ph)) * lo2[qh + 4 - j]
         + tap(FARQ, M, 1, 9 - (2 * j + ph)) * h2[qh + 4 - j];
    }
    acc[nh] += v;
  }
}

// ---------------- Stage A: q-shift level (128 -> 256), one quadrant per block ----------------
template<int M, int N>
__device__ __forceinline__ void qshift_body(const float* __restrict__ w2, const float* __restrict__ loT,
                                            float* __restrict__ mid, float* __restrict__ sIn,
                                            int b, int th, int tw, int tid) {
  const int c = tid & 15, s = tid >> 4;
  const int ih0 = th * 8, iw0 = tw * 8;
  constexpr int j1 = M ^ N;
  constexpr float sgn = M ? -1.0f : 1.0f;
  const size_t plane = (size_t)128 * 128 * 16;

  stage_copy<128>(loT + ((size_t)((M * 2 + N) * 4 + b)) * plane, sIn + 0 * 2304, ih0, iw0, tid);
  stage_mix<128>(w2 + ((size_t)((0 * 2 + j1) * 3 + 0) * 4 + b) * plane,
                 w2 + ((size_t)((1 * 2 + (1 ^ j1)) * 3 + 0) * 4 + b) * plane,
                 sgn, sIn + 1 * 2304, ih0, iw0, tid);
  stage_mix<128>(w2 + ((size_t)((0 * 2 + j1) * 3 + 1) * 4 + b) * plane,
                 w2 + ((size_t)((1 * 2 + (1 ^ j1)) * 3 + 1) * 4 + b) * plane,
                 sgn, sIn + 2 * 2304, ih0, iw0, tid);
  stage_mix<128>(w2 + ((size_t)((0 * 2 + j1) * 3 + 2) * 4 + b) * plane,
                 w2 + ((size_t)((1 * 2 + (1 ^ j1)) * 3 + 2) * 4 + b) * plane,
                 sgn, sIn + 3 * 2304, ih0, iw0, tid);
  __syncthreads();

  float acc[16];
  #pragma unroll
  for (int i = 0; i < 16; ++i) acc[i] = 0.f;
  synth_quad<false, M, N>(sIn, s, c, acc);

  float* outQ = mid + ((size_t)((M * 2 + N) * 4 + b)) * (size_t)(256 * 256 * 16);
  #pragma unroll
  for (int nh = 0; nh < 16; ++nh) {
    outQ[(((size_t)(ih0 * 2 + nh)) * 256 + (size_t)(iw0 * 2 + s)) * 16 + c] = acc[nh];
  }
}

__global__ __launch_bounds__(256, 4) void qshift_kernel(
    const float* __restrict__ w2, const float* __restrict__ loT, float* __restrict__ mid) {
  __shared__ float sIn[4 * 2304];
  const int tid = threadIdx.x;
  const int tw = blockIdx.x, th = blockIdx.y;
  const int b = blockIdx.z & 3, q = blockIdx.z >> 2;
  switch (q) {
    case 0: qshift_body<0, 0>(w2, loT, mid, sIn, b, th, tw, tid); break;
    case 1: qshift_body<0, 1>(w2, loT, mid, sIn, b, th, tw, tid); break;
    case 2: qshift_body<1, 0>(w2, loT, mid, sIn, b, th, tw, tid); break;
    default: qshift_body<1, 1>(w2, loT, mid, sIn, b, th, tw, tid); break;
  }
}

// ---------------- Stage B: Farras level (256 -> 512), sums 4 quadrants ----------------
__global__ __launch_bounds__(256, 4) void farras_kernel(
    const float* __restrict__ w1, const float* __restrict__ mid, float* __restrict__ out) {
  __shared__ float sIn[4 * 2304];
  const int tid = threadIdx.x;
  const int c = tid & 15, s = tid >> 4;
  const int tw = blockIdx.x, th = blockIdx.y, b = blockIdx.z;
  const int ih0 = th * 8, iw0 = tw * 8;
  const size_t plane = (size_t)256 * 256 * 16;

  float acc[16];
  #pragma unroll
  for (int i = 0; i < 16; ++i) acc[i] = 0.f;

#define DO_QUAD(M_, N_)                                                                        \
  {                                                                                            \
    constexpr int j1 = (M_) ^ (N_);                                                            \
    constexpr float sgn = (M_) ? -1.0f : 1.0f;                                                 \
    stage_copy<256>(mid + ((size_t)(((M_)*2 + (N_)) * 4 + b)) * plane, sIn + 0 * 2304,         \
                    ih0, iw0, tid);                                                            \
    stage_mix<256>(w1 + ((size_t)((0 * 2 + j1) * 3 + 0) * 4 + b) * plane,                      \
                   w1 + ((size_t)((1 * 2 + (1 ^ j1)) * 3 + 0) * 4 + b) * plane,                \
                   sgn, sIn + 1 * 2304, ih0, iw0, tid);                                        \
    stage_mix<256>(w1 + ((size_t)((0 * 2 + j1) * 3 + 1) * 4 + b) * plane,                      \
                   w1 + ((size_t)((1 * 2 + (1 ^ j1)) * 3 + 1) * 4 + b) * plane,                \
                   sgn, sIn + 2 * 2304, ih0, iw0, tid);                                        \
    stage_mix<256>(w1 + ((size_t)((0 * 2 + j1) * 3 + 2) * 4 + b) * plane,                      \
                   w1 + ((size_t)((1 * 2 + (1 ^ j1)) * 3 + 2) * 4 + b) * plane,                \
                   sgn, sIn + 3 * 2304, ih0, iw0, tid);                                        \
    __syncthreads();                                                                           \
    synth_quad<true, M_, N_>(sIn, s, c, acc);                                                  \
    __syncthreads();                                                                           \
  }

  DO_QUAD(0, 0)
  DO_QUAD(0, 1)
  DO_QUAD(1, 0)
  DO_QUAD(1, 1)
#undef DO_QUAD

  #pragma unroll
  for (int nh = 0; nh < 16; ++nh) {
    size_t gh = (size_t)(ih0 * 2 + nh);
    size_t gw = (size_t)(iw0 * 2 + s);
    out[(((size_t)b * 512 + gh) * 512 + gw) * 16 + c] = acc[nh] * 0.5f;
  }
}

extern "C" void kernel_launch(void* const* d_in, const int* in_sizes, int n_in,
                              void* d_out, int out_size, void* d_ws, size_t ws_size,
                              hipStream_t stream) {
  const float* w1 = (const float*)d_in[0];   // [2,2,3,4,256,256,16]
  const float* w2 = (const float*)d_in[1];   // [2,2,3,4,128,128,16]
  const float* lo = (const float*)d_in[2];   // [2,2,4,128,128,16]
  float* out = (float*)d_out;                // [4,512,512,16]
  float* mid = (float*)d_ws;                 // [4 quadrants][4][256][256][16] = 64 MiB

  qshift_kernel<<<dim3(16, 16, 16), 256, 0, stream>>>(w2, lo, mid);
  farras_kernel<<<dim3(32, 32, 4), 256, 0, stream>>>(w1, mid, out);
}

// Round 3
// 863.634 us; speedup vs baseline: 2.2858x; 2.2858x over previous
//
#include <hip/hip_runtime.h>

#define INV_SQRT2f 0.70710678118654752440f

// Analysis filters (compile-time; synthesis tap f[k] = AF[9-k], folded at call sites).
// Polyphase synthesis: out[2q+p] = sum_{j=0..4} AF[9-(2j+p)] * x[(q+2-j) mod Nin]
constexpr float FARv[2][2][10] = {
  {{0.0f, -0.08838834764832f, 0.08838834764832f, 0.69587998903400f, 0.69587998903400f,
    0.08838834764832f, -0.08838834764832f, 0.01122679215254f, 0.01122679215254f, 0.0f},
   {0.0f, -0.01122679215254f, 0.01122679215254f, 0.08838834764832f, 0.08838834764832f,
    -0.69587998903400f, 0.69587998903400f, -0.08838834764832f, -0.08838834764832f, 0.0f}},
  {{0.01122679215254f, 0.01122679215254f, -0.08838834764832f, 0.08838834764832f, 0.69587998903400f,
    0.69587998903400f, 0.08838834764832f, -0.08838834764832f, 0.0f, 0.0f},
   {0.0f, 0.0f, -0.08838834764832f, -0.08838834764832f, 0.69587998903400f,
    -0.69587998903400f, 0.08838834764832f, 0.08838834764832f, 0.01122679215254f, -0.01122679215254f}}
};
constexpr float DUALv[2][2][10] = {
  {{0.03516384f, 0.0f, -0.08832942f, 0.23389032f, 0.76027237f,
    0.58751830f, 0.0f, -0.11430184f, 0.0f, 0.0f},
   {0.0f, 0.0f, -0.11430184f, 0.0f, 0.58751830f,
    -0.76027237f, 0.23389032f, 0.08832942f, 0.0f, -0.03516384f}},
  {{0.0f, 0.0f, -0.11430184f, 0.0f, 0.58751830f,
    0.76027237f, 0.23389032f, -0.08832942f, 0.0f, 0.03516384f},
   {-0.03516384f, 0.0f, 0.08832942f, 0.23389032f, -0.76027237f,
    0.58751830f, 0.0f, -0.11430184f, 0.0f, 0.0f}}
};

__host__ __device__ constexpr float tap(bool farq, int t, int lh, int k) {
  return (k < 0 || k > 9) ? 0.0f : (farq ? FARv[t][lh][k] : DUALv[t][lh][k]);
}

// ---- staging: 12x12 spatial halo tile x 16 ch = 576 float4, 256 threads ----
template<int NSZ>
__device__ __forceinline__ void stage_copy(const float* __restrict__ src, float* __restrict__ dst,
                                           int ih0, int iw0, int tid) {
  #pragma unroll
  for (int it = 0; it < 3; ++it) {
    int e = tid + (it << 8);
    if (it < 2 || e < 576) {
      int r = e / 48;
      int cc = e - r * 48;
      int gr = (ih0 + r - 2) & (NSZ - 1);
      int gc = (iw0 + (cc >> 2) - 2) & (NSZ - 1);
      float4 v = *reinterpret_cast<const float4*>(src + (((size_t)gr * NSZ + gc) << 4) + ((cc & 3) << 2));
      *reinterpret_cast<float4*>(dst + (e << 2)) = v;
    }
  }
}

template<int NSZ>
__device__ __forceinline__ void stage_mix(const float* __restrict__ A, const float* __restrict__ B,
                                          float sgn, float* __restrict__ dst,
                                          int ih0, int iw0, int tid) {
  #pragma unroll
  for (int it = 0; it < 3; ++it) {
    int e = tid + (it << 8);
    if (it < 2 || e < 576) {
      int r = e / 48;
      int cc = e - r * 48;
      int gr = (ih0 + r - 2) & (NSZ - 1);
      int gc = (iw0 + (cc >> 2) - 2) & (NSZ - 1);
      size_t off = (((size_t)gr * NSZ + gc) << 4) + ((cc & 3) << 2);
      float4 a = *reinterpret_cast<const float4*>(A + off);
      float4 b = *reinterpret_cast<const float4*>(B + off);
      float4 v;
      v.x = (a.x + sgn * b.x) * INV_SQRT2f;
      v.y = (a.y + sgn * b.y) * INV_SQRT2f;
      v.z = (a.z + sgn * b.z) * INV_SQRT2f;
      v.w = (a.w + sgn * b.w) * INV_SQRT2f;
      *reinterpret_cast<float4*>(dst + (e << 2)) = v;
    }
  }
}

// scatter-accumulate helper: coefficients AF[2*(r-t)+1-p]; zeros fold away
template<bool FARQ, int M>
__device__ __forceinline__ void scatter_accum(float (&acc)[16], int t, int r, float lv, float hv) {
  acc[2 * t]     += tap(FARQ, M, 0, 2 * (r - t) + 1) * lv + tap(FARQ, M, 1, 2 * (r - t) + 1) * hv;
  acc[2 * t + 1] += tap(FARQ, M, 0, 2 * (r - t))     * lv + tap(FARQ, M, 1, 2 * (r - t))     * hv;
}

// ---- per-quadrant synthesis ----
// Col pass (LDS -> lv/hv), then SCATTER-accumulate row pass (no private arrays,
// no sMid LDS): col-row r contributes to out rows 2t+p for t in [r-4, r] & [0,7].
// sIn layout: [plane(4)][r(12)][x(12)][c(16)]; thread owns (out-col nw=s, channel c).
template<bool FARQ, int M, int N>
__device__ __forceinline__ void synth_quad(const float* __restrict__ sIn, int s, int c,
                                           float (&acc)[16]) {
  const int pw = s & 1, qw = s >> 1;
  const float* base = sIn + c;
  #pragma unroll
  for (int r = 0; r < 12; ++r) {
    const float* r0 = base + (0 * 12 + r) * 192;
    const float* r1 = base + (1 * 12 + r) * 192;
    const float* r2 = base + (2 * 12 + r) * 192;
    const float* r3 = base + (3 * 12 + r) * 192;
    float lv = 0.f, hv = 0.f;
    #pragma unroll
    for (int j = 0; j < 5; ++j) {
      // col-pass taps: AF[9-(2j+pw)], runtime select between two constants
      float fl = pw ? tap(FARQ, N, 0, 8 - 2 * j) : tap(FARQ, N, 0, 9 - 2 * j);
      float fh = pw ? tap(FARQ, N, 1, 8 - 2 * j) : tap(FARQ, N, 1, 9 - 2 * j);
      int x = (qw + 4 - j) << 4;
      lv += fl * r0[x] + fh * r1[x];
      hv += fl * r2[x] + fh * r3[x];
    }
    #pragma unroll
    for (int t = 0; t < 8; ++t) {
      if (t >= r - 4 && t <= r) {  // compile-time predicate after unroll
        scatter_accum<FARQ, M>(acc, t, r, lv, hv);
      }
    }
  }
}

// ---------------- Stage A: q-shift level (128 -> 256), one quadrant per block ----------------
template<int M, int N>
__device__ __forceinline__ void qshift_body(const float* __restrict__ w2, const float* __restrict__ loT,
                                            float* __restrict__ mid, float* __restrict__ sIn,
                                            int b, int th, int tw, int tid) {
  const int c = tid & 15, s = tid >> 4;
  const int ih0 = th * 8, iw0 = tw * 8;
  constexpr int j1 = M ^ N;
  constexpr float sgn = M ? -1.0f : 1.0f;
  const size_t plane = (size_t)128 * 128 * 16;

  stage_copy<128>(loT + ((size_t)((M * 2 + N) * 4 + b)) * plane, sIn + 0 * 2304, ih0, iw0, tid);
  stage_mix<128>(w2 + ((size_t)((0 * 2 + j1) * 3 + 0) * 4 + b) * plane,
                 w2 + ((size_t)((1 * 2 + (1 ^ j1)) * 3 + 0) * 4 + b) * plane,
                 sgn, sIn + 1 * 2304, ih0, iw0, tid);
  stage_mix<128>(w2 + ((size_t)((0 * 2 + j1) * 3 + 1) * 4 + b) * plane,
                 w2 + ((size_t)((1 * 2 + (1 ^ j1)) * 3 + 1) * 4 + b) * plane,
                 sgn, sIn + 2 * 2304, ih0, iw0, tid);
  stage_mix<128>(w2 + ((size_t)((0 * 2 + j1) * 3 + 2) * 4 + b) * plane,
                 w2 + ((size_t)((1 * 2 + (1 ^ j1)) * 3 + 2) * 4 + b) * plane,
                 sgn, sIn + 3 * 2304, ih0, iw0, tid);
  __syncthreads();

  float acc[16];
  #pragma unroll
  for (int i = 0; i < 16; ++i) acc[i] = 0.f;
  synth_quad<false, M, N>(sIn, s, c, acc);

  float* outQ = mid + ((size_t)((M * 2 + N) * 4 + b)) * (size_t)(256 * 256 * 16);
  #pragma unroll
  for (int nh = 0; nh < 16; ++nh) {
    outQ[(((size_t)(ih0 * 2 + nh)) * 256 + (size_t)(iw0 * 2 + s)) * 16 + c] = acc[nh];
  }
}

__global__ __launch_bounds__(256) void qshift_kernel(
    const float* __restrict__ w2, const float* __restrict__ loT, float* __restrict__ mid) {
  __shared__ float sIn[4 * 2304];
  const int tid = threadIdx.x;
  const int tw = blockIdx.x, th = blockIdx.y;
  const int b = blockIdx.z & 3, q = blockIdx.z >> 2;
  switch (q) {
    case 0: qshift_body<0, 0>(w2, loT, mid, sIn, b, th, tw, tid); break;
    case 1: qshift_body<0, 1>(w2, loT, mid, sIn, b, th, tw, tid); break;
    case 2: qshift_body<1, 0>(w2, loT, mid, sIn, b, th, tw, tid); break;
    default: qshift_body<1, 1>(w2, loT, mid, sIn, b, th, tw, tid); break;
  }
}

// ---------------- Stage B: Farras level (256 -> 512), sums 4 quadrants ----------------
__global__ __launch_bounds__(256) void farras_kernel(
    const float* __restrict__ w1, const float* __restrict__ mid, float* __restrict__ out) {
  __shared__ float sIn[4 * 2304];
  const int tid = threadIdx.x;
  const int c = tid & 15, s = tid >> 4;
  const int tw = blockIdx.x, th = blockIdx.y, b = blockIdx.z;
  const int ih0 = th * 8, iw0 = tw * 8;
  const size_t plane = (size_t)256 * 256 * 16;

  float acc[16];
  #pragma unroll
  for (int i = 0; i < 16; ++i) acc[i] = 0.f;

#define DO_QUAD(M_, N_)                                                                        \
  {                                                                                            \
    constexpr int j1 = (M_) ^ (N_);                                                            \
    constexpr float sgn = (M_) ? -1.0f : 1.0f;                                                 \
    stage_copy<256>(mid + ((size_t)(((M_)*2 + (N_)) * 4 + b)) * plane, sIn + 0 * 2304,         \
                    ih0, iw0, tid);                                                            \
    stage_mix<256>(w1 + ((size_t)((0 * 2 + j1) * 3 + 0) * 4 + b) * plane,                      \
                   w1 + ((size_t)((1 * 2 + (1 ^ j1)) * 3 + 0) * 4 + b) * plane,                \
                   sgn, sIn + 1 * 2304, ih0, iw0, tid);                                        \
    stage_mix<256>(w1 + ((size_t)((0 * 2 + j1) * 3 + 1) * 4 + b) * plane,                      \
                   w1 + ((size_t)((1 * 2 + (1 ^ j1)) * 3 + 1) * 4 + b) * plane,                \
                   sgn, sIn + 2 * 2304, ih0, iw0, tid);                                        \
    stage_mix<256>(w1 + ((size_t)((0 * 2 + j1) * 3 + 2) * 4 + b) * plane,                      \
                   w1 + ((size_t)((1 * 2 + (1 ^ j1)) * 3 + 2) * 4 + b) * plane,                \
                   sgn, sIn + 3 * 2304, ih0, iw0, tid);                                        \
    __syncthreads();                                                                           \
    synth_quad<true, M_, N_>(sIn, s, c, acc);                                                  \
    __syncthreads();                                                                           \
  }

  DO_QUAD(0, 0)
  DO_QUAD(0, 1)
  DO_QUAD(1, 0)
  DO_QUAD(1, 1)
#undef DO_QUAD

  #pragma unroll
  for (int nh = 0; nh < 16; ++nh) {
    size_t gh = (size_t)(ih0 * 2 + nh);
    size_t gw = (size_t)(iw0 * 2 + s);
    out[(((size_t)b * 512 + gh) * 512 + gw) * 16 + c] = acc[nh] * 0.5f;
  }
}

extern "C" void kernel_launch(void* const* d_in, const int* in_sizes, int n_in,
                              void* d_out, int out_size, void* d_ws, size_t ws_size,
                              hipStream_t stream) {
  const float* w1 = (const float*)d_in[0];   // [2,2,3,4,256,256,16]
  const float* w2 = (const float*)d_in[1];   // [2,2,3,4,128,128,16]
  const float* lo = (const float*)d_in[2];   // [2,2,4,128,128,16]
  float* out = (float*)d_out;                // [4,512,512,16]
  float* mid = (float*)d_ws;                 // [4 quadrants][4][256][256][16] = 64 MiB

  qshift_kernel<<<dim3(16, 16, 16), 256, 0, stream>>>(w2, lo, mid);
  farras_kernel<<<dim3(32, 32, 4), 256, 0, stream>>>(w1, mid, out);
}